// Round 8
// baseline (170.806 us; speedup 1.0000x reference)
//
#include <hip/hip_runtime.h>
#include <math.h>

#define NB 4
#define NL 2048
#define ND 768
#define NH 12
#define NK 9
#define NIPG 64
#define NPAD 4
#define MT 240          // output rows per gemm_conv block (computes 256 v-rows)

typedef __attribute__((ext_vector_type(8))) short s16x8;
typedef __attribute__((ext_vector_type(4))) float f32x4;

__device__ __forceinline__ unsigned short f2bf(float f) {
  unsigned int u = __float_as_uint(f);
  unsigned int r = (u + 0x7FFFu + ((u >> 16) & 1u)) >> 16;
  return (unsigned short)r;
}
__device__ __forceinline__ float bf2f(unsigned short s) {
  return __uint_as_float(((unsigned int)s) << 16);
}
__device__ __forceinline__ void gload16(const void* g, void* l) {
  __builtin_amdgcn_global_load_lds((const __attribute__((address_space(1))) void*)g,
                                   (__attribute__((address_space(3))) void*)l,
                                   16, 0, 0);
}

// ---------------------------------------------------------------------------
// Kernel 0: weight prep — pt_w -> ptb (bf16), pw_w -> pwb, ak_w -> akp
// ---------------------------------------------------------------------------
__global__ __launch_bounds__(256) void prep(const float* __restrict__ pt_w,
                                            const float* __restrict__ pw_w,
                                            const float* __restrict__ ak_w,
                                            unsigned short* __restrict__ ptb,
                                            unsigned short* __restrict__ pwb,
                                            unsigned short* __restrict__ akp) {
  const int t = blockIdx.x * 256 + threadIdx.x;
  if (t < ND * ND / 4) {
    float4 f = ((const float4*)pt_w)[t];
    ushort4 o; o.x = f2bf(f.x); o.y = f2bf(f.y); o.z = f2bf(f.z); o.w = f2bf(f.w);
    ((ushort4*)ptb)[t] = o;
  }
  if (t < NH * NIPG * NIPG / 4) {
    float4 f = ((const float4*)pw_w)[t];
    ushort4 o; o.x = f2bf(f.x); o.y = f2bf(f.y); o.z = f2bf(f.z); o.w = f2bf(f.w);
    ((ushort4*)pwb)[t] = o;
  }
  if (t < NH * 16 * NIPG) {
    const int h = t >> 10;
    const int r = t & 1023;
    const int k = r >> 6;
    const int i = r & 63;
    akp[t] = (k < NK) ? f2bf(ak_w[((size_t)h * NK + k) * NIPG + i]) : (unsigned short)0;
  }
}

// ---------------------------------------------------------------------------
// Kernel 1: dynamic conv weights (MFMA) + emits qb = bf16(query).
// Unchanged from round 7 (passed).
// ---------------------------------------------------------------------------
__global__ __launch_bounds__(256) void attn_w(const float* __restrict__ q,
                                              const float* __restrict__ dw_w,
                                              const unsigned short* __restrict__ pwb,
                                              const float* __restrict__ pw_b,
                                              const unsigned short* __restrict__ akp,
                                              const float* __restrict__ ak_b,
                                              float* __restrict__ wout,
                                              unsigned short* __restrict__ qb) {
  __shared__ unsigned short qs[72][68];
  __shared__ unsigned char ab[8192];
  const int l0 = blockIdx.x * 64;
  const int h  = blockIdx.y;
  const int b  = blockIdx.z;
  const int d0 = h * NIPG;
  const int t  = threadIdx.x;
  const int lane = t & 63;
  const int wv = t >> 6;
  const int fr = lane & 15;
  const int fq = lane >> 4;

  const unsigned short* pwh = pwb + (size_t)h * NIPG * NIPG;
  const unsigned short* akh = akp + (size_t)h * 16 * NIPG;
  s16x8 pv0[4], pv1[4];
#pragma unroll
  for (int n = 0; n < 4; ++n) {
    const int o = n * 16 + fr;
    pv0[n] = *(const s16x8*)&pwh[o * 64 + fq * 8];
    pv1[n] = *(const s16x8*)&pwh[o * 64 + 32 + fq * 8];
  }
  s16x8 ak0 = *(const s16x8*)&akh[fr * 64 + fq * 8];
  s16x8 ak1 = *(const s16x8*)&akh[fr * 64 + 32 + fq * 8];
  float dwk[NK];
#pragma unroll
  for (int k = 0; k < NK; ++k) dwk[k] = dw_w[(size_t)(d0 + lane) * NK + k];

  {
    const int sl = t >> 4;
    const int sc = (t & 15) * 4;
    for (int r = sl; r < 72; r += 16) {
      const int l = l0 - NPAD + r;
      ushort4 ub = make_ushort4(0, 0, 0, 0);
      if (l >= 0 && l < NL) {
        float4 val = *(const float4*)&q[((size_t)(b * NL + l)) * ND + d0 + sc];
        ub.x = f2bf(val.x); ub.y = f2bf(val.y); ub.z = f2bf(val.z); ub.w = f2bf(val.w);
        if (r >= NPAD && r < NPAD + 64)
          *(ushort4*)&qb[((size_t)(b * NL + l)) * ND + d0 + sc] = ub;
      }
      *(ushort4*)&qs[r][sc] = ub;
    }
  }
  __syncthreads();

  const int lset = wv * 16;
  {
    float win9[NK];
#pragma unroll
    for (int k = 0; k < NK; ++k) win9[k] = bf2f(qs[lset + k][lane]);
#pragma unroll
    for (int l2 = 0; l2 < 16; ++l2) {
      const int l = lset + l2;
      float s = 0.f;
#pragma unroll
      for (int k = 0; k < NK; ++k) s = fmaf(win9[k], dwk[k], s);
      const int byte = ((l * 64 + lane) * 2) ^ ((l & 7) << 4);
      *(unsigned short*)&ab[byte] = f2bf(s);
      if (l2 < 15) {
#pragma unroll
        for (int k = 0; k < NK - 1; ++k) win9[k] = win9[k + 1];
        win9[NK - 1] = bf2f(qs[lset + l2 + NK][lane]);
      }
    }
  }

  s16x8 av0, av1;
  {
    const int row = lset + fr;
    const int b0 = ((row * 64 + fq * 8) * 2)      ^ ((row & 7) << 4);
    const int b1 = ((row * 64 + 32 + fq * 8) * 2) ^ ((row & 7) << 4);
    av0 = *(const s16x8*)&ab[b0];
    av1 = *(const s16x8*)&ab[b1];
  }
  f32x4 accp[4];
#pragma unroll
  for (int n = 0; n < 4; ++n) {
    accp[n] = (f32x4){0.f, 0.f, 0.f, 0.f};
    accp[n] = __builtin_amdgcn_mfma_f32_16x16x32_bf16(av0, pv0[n], accp[n], 0, 0, 0);
    accp[n] = __builtin_amdgcn_mfma_f32_16x16x32_bf16(av1, pv1[n], accp[n], 0, 0, 0);
  }

#pragma unroll
  for (int n = 0; n < 4; ++n) {
    const int o = n * 16 + fr;
    const float pb = pw_b[d0 + o];
#pragma unroll
    for (int j = 0; j < 4; ++j) {
      const int row = lset + fq * 4 + j;
      const float ca = (accp[n][j] + pb) * bf2f(qs[row + NPAD][o]);
      const int byte = ((row * 64 + o) * 2) ^ ((row & 7) << 4);
      *(unsigned short*)&ab[byte] = f2bf(ca);
    }
  }

  f32x4 acck = (f32x4){0.f, 0.f, 0.f, 0.f};
  {
    const int row = lset + fr;
    const int b0 = ((row * 64 + fq * 8) * 2)      ^ ((row & 7) << 4);
    const int b1 = ((row * 64 + 32 + fq * 8) * 2) ^ ((row & 7) << 4);
    s16x8 a0 = *(const s16x8*)&ab[b0];
    s16x8 a1 = *(const s16x8*)&ab[b1];
    acck = __builtin_amdgcn_mfma_f32_16x16x32_bf16(a0, ak0, acck, 0, 0, 0);
    acck = __builtin_amdgcn_mfma_f32_16x16x32_bf16(a1, ak1, acck, 0, 0, 0);
  }

  const bool kvalid = fr < NK;
  const float akbv = kvalid ? ak_b[h * NK + fr] : 0.f;
#pragma unroll
  for (int j = 0; j < 4; ++j) {
    float val = acck[j] + akbv;
    float mv = kvalid ? val : -3.4e38f;
#pragma unroll
    for (int mm = 1; mm < 16; mm <<= 1) mv = fmaxf(mv, __shfl_xor(mv, mm));
    const float e = kvalid ? __expf(val - mv) : 0.f;
    float ssum = e;
#pragma unroll
    for (int mm = 1; mm < 16; mm <<= 1) ssum += __shfl_xor(ssum, mm);
    if (kvalid) {
      const int row = l0 + lset + fq * 4 + j;
      wout[(((size_t)(b * NL + row)) * NH + h) * NK + fr] = e / ssum;
    }
  }
}

// ---------------------------------------------------------------------------
// Kernel 2: fused v-GEMM + 9-tap conv — wave-independent streaming design.
// Block = 256 v-rows x 64 cols (one head).  B (64x768, 96KB) staged to LDS
// ONCE; after one barrier the K-loop has ZERO barriers: each wave streams its
// own 64 A-rows global->VGPR (quarter-K double-buffer, 24 loads in flight)
// against read-only LDS B, each bv ds_read feeding 4 MFMAs.  Grid 420 linear
// + bijective chunked XCD swizzle (m204) so the 12 blocks sharing an A-panel
// land on one XCD (panel becomes L2-resident).  LDS 130KB -> 1 block/CU.
// ---------------------------------------------------------------------------
__global__ __launch_bounds__(256) void gemm_conv(const unsigned short* __restrict__ qb,
                                                 const unsigned short* __restrict__ ptb,
                                                 const float* __restrict__ bias,
                                                 const float* __restrict__ w,
                                                 float* __restrict__ out) {
  __shared__ unsigned char Bl[98304];       // [24 kt][64 c][64B]
  __shared__ unsigned short vt[256 * 68];   // 34.8KB v-tile
  const int t = threadIdx.x;
  // bijective chunked XCD swizzle, nwg = 420 (m204)
  const int orig = blockIdx.x;
  const int q8 = 420 >> 3, r8 = 420 & 7;
  const int xcd = orig & 7, loc = orig >> 3;
  const int wgid = (xcd < r8 ? xcd * (q8 + 1) : r8 * (q8 + 1) + (xcd - r8) * q8) + loc;
  const long mo = (long)(wgid / 12) * MT;
  const int n0 = (wgid % 12) * 64;
  const int lane = t & 63;
  const int wv = t >> 6;
  const int fr = lane & 15;
  const int fq = lane >> 4;

  // ---- B stage: 24 gload16/thread into linear Bl; kt=round, c=t>>2 ----
  {
    const unsigned char* gsrc =
        (const unsigned char*)ptb + (size_t)(n0 + (t >> 2)) * 1536 + (t & 3) * 16;
    unsigned char* ldst = &Bl[t * 16];
#pragma unroll
    for (int r = 0; r < 24; ++r)
      gload16(gsrc + r * 64, ldst + r * 4096);
  }
  __builtin_amdgcn_sched_barrier(0);   // pin: all B gloads issue before A loads

  // ---- A fragment loads: wave wv owns rel rows [wv*64, wv*64+64) ----
  const unsigned short* pa = qb + (mo - 8 + wv * 64 + fr) * (long)ND + fq * 8;
  s16x8 af0[4][6], af1[4][6];          // quarter-K double buffer (2x24 frags)
  f32x4 acc[4][4] = {};

#define LOADA(buf, qq)                                                      \
  do {                                                                      \
    _Pragma("unroll")                                                       \
    for (int m_ = 0; m_ < 4; ++m_)                                          \
      _Pragma("unroll")                                                     \
      for (int j_ = 0; j_ < 6; ++j_)                                        \
        buf[m_][j_] = *(const s16x8*)(pa + (long)m_ * 16 * ND + ((qq) * 6 + j_) * 32); \
  } while (0)

#define COMPQ(buf, qq)                                                      \
  do {                                                                      \
    _Pragma("unroll")                                                       \
    for (int j_ = 0; j_ < 6; ++j_) {                                        \
      const int kt_ = (qq) * 6 + j_;                                        \
      _Pragma("unroll")                                                     \
      for (int n_ = 0; n_ < 4; ++n_) {                                      \
        s16x8 bv_ = *(const s16x8*)&Bl[kt_ * 4096 + (n_ * 16 + fr) * 64 + fq * 16]; \
        _Pragma("unroll")                                                   \
        for (int m_ = 0; m_ < 4; ++m_)                                      \
          acc[m_][n_] = __builtin_amdgcn_mfma_f32_16x16x32_bf16(            \
              buf[m_][j_], bv_, acc[m_][n_], 0, 0, 0);                      \
      }                                                                     \
    }                                                                       \
  } while (0)

  LOADA(af0, 0);
  LOADA(af1, 1);
  asm volatile("s_waitcnt vmcnt(48)" ::: "memory");   // 24 oldest (=B) done
  __builtin_amdgcn_s_barrier();                       // B visible to all waves
  __builtin_amdgcn_sched_barrier(0);

  COMPQ(af0, 0);          // A q0 waits arrive naturally (compiler vmcnt)
  LOADA(af0, 2);          // overlaps q1 compute
  COMPQ(af1, 1);
  LOADA(af1, 3);          // overlaps q2 compute
  COMPQ(af0, 2);
  COMPQ(af1, 3);
#undef LOADA
#undef COMPQ

  // ---- dump v-tile (+bias) to LDS bf16, [256][68] ----
#pragma unroll
  for (int m = 0; m < 4; ++m) {
#pragma unroll
    for (int n = 0; n < 4; ++n) {
      const int rb = wv * 64 + m * 16 + fq * 4;
      const int cc = n * 16 + fr;
      const float bbv = bias[n0 + cc];
#pragma unroll
      for (int j = 0; j < 4; ++j)
        vt[(rb + j) * 68 + cc] = f2bf(acc[m][n][j] + bbv);
    }
  }
  __syncthreads();

  // ---- conv tail: thread owns col-quad cq, 15 rows (rel 8..247) ----
  const int cq = (t & 15) * 4;
  const int r0 = 8 + (t >> 4) * 15;
  const int h = n0 >> 6;
  float4 win[NK];
#pragma unroll
  for (int k = 0; k < NK; ++k) {
    ushort4 u = *(const ushort4*)&vt[(r0 - 4 + k) * 68 + cq];
    win[k] = make_float4(bf2f(u.x), bf2f(u.y), bf2f(u.z), bf2f(u.w));
  }
#pragma unroll
  for (int i = 0; i < 15; ++i) {
    const int r = r0 + i;
    const long g = mo + r - 8;
    if (g < (long)NB * NL) {
      const int l = (int)(g & (NL - 1));
      const float* wp = &w[((size_t)g * NH + h) * NK];
      float4 a = make_float4(0.f, 0.f, 0.f, 0.f);
#pragma unroll
      for (int k = 0; k < NK; ++k) {
        const int lk = l + k - NPAD;
        if (lk >= 0 && lk < NL) {
          const float wk = wp[k];
          a.x = fmaf(wk, win[k].x, a.x);
          a.y = fmaf(wk, win[k].y, a.y);
          a.z = fmaf(wk, win[k].z, a.z);
          a.w = fmaf(wk, win[k].w, a.w);
        }
      }
      *(float4*)&out[(size_t)g * ND + n0 + cq] = a;
    }
    if (i < 14) {
#pragma unroll
      for (int k = 0; k < NK - 1; ++k) win[k] = win[k + 1];
      ushort4 u = *(const ushort4*)&vt[(r + 5) * 68 + cq];
      win[NK - 1] = make_float4(bf2f(u.x), bf2f(u.y), bf2f(u.z), bf2f(u.w));
    }
  }
}

// ---------------------------------------------------------------------------
extern "C" void kernel_launch(void* const* d_in, const int* in_sizes, int n_in,
                              void* d_out, int out_size, void* d_ws, size_t ws_size,
                              hipStream_t stream) {
  const float* query = (const float*)d_in[0];
  const float* dw_w  = (const float*)d_in[1];
  const float* pw_w  = (const float*)d_in[2];
  const float* pw_b  = (const float*)d_in[3];
  const float* ak_w  = (const float*)d_in[4];
  const float* ak_b  = (const float*)d_in[5];
  const float* pt_w  = (const float*)d_in[6];
  const float* pt_b  = (const float*)d_in[7];
  float* out = (float*)d_out;

  // workspace: w first (gives qb a safe apron both sides), then qb, ptb…
  float* w = (float*)d_ws;                                        // 3.54MB
  unsigned short* qb  = (unsigned short*)(w + (size_t)NB * NL * NH * NK); // 12.6MB
  unsigned short* ptb = qb + (size_t)NB * NL * ND;                // 1.18MB
  unsigned short* pwb = ptb + (size_t)ND * ND;                    // 98KB
  unsigned short* akp = pwb + (size_t)NH * NIPG * NIPG;           // 24.6KB

  prep<<<ND * ND / 4 / 256, 256, 0, stream>>>(pt_w, pw_w, ak_w, ptb, pwb, akp);

  dim3 g2(NL / 64, NH, NB);
  attn_w<<<g2, 256, 0, stream>>>(query, dw_w, pwb, pw_b, akp, ak_b, w, qb);

  gemm_conv<<<35 * 12, 256, 0, stream>>>(qb, ptb, pt_b, w, out);
}

// Round 9
// 139.875 us; speedup vs baseline: 1.2211x; 1.2211x over previous
//
#include <hip/hip_runtime.h>
#include <math.h>

#define NB 4
#define NL 2048
#define ND 768
#define NH 12
#define NK 9
#define NIPG 64
#define NPAD 4
#define LT 16
#define NGEMM 768     // gemm blocks in fused launch (64 m-panels x 12 n)

typedef __attribute__((ext_vector_type(8))) short s16x8;
typedef __attribute__((ext_vector_type(4))) float f32x4;

__device__ __forceinline__ unsigned short f2bf(float f) {
  unsigned int u = __float_as_uint(f);
  unsigned int r = (u + 0x7FFFu + ((u >> 16) & 1u)) >> 16;
  return (unsigned short)r;
}
__device__ __forceinline__ float bf2f(unsigned short s) {
  return __uint_as_float(((unsigned int)s) << 16);
}
__device__ __forceinline__ void gload16(const void* g, void* l) {
  __builtin_amdgcn_global_load_lds((const __attribute__((address_space(1))) void*)g,
                                   (__attribute__((address_space(3))) void*)l,
                                   16, 0, 0);
}

// ---------------------------------------------------------------------------
// Kernel 0: prep — q -> qb (bf16, grid-stride), pt_w -> ptb, pw_w -> pwb,
// ak_w -> akp (k-padded to 16).
// ---------------------------------------------------------------------------
__global__ __launch_bounds__(256) void prep(const float* __restrict__ q,
                                            const float* __restrict__ pt_w,
                                            const float* __restrict__ pw_w,
                                            const float* __restrict__ ak_w,
                                            unsigned short* __restrict__ qb,
                                            unsigned short* __restrict__ ptb,
                                            unsigned short* __restrict__ pwb,
                                            unsigned short* __restrict__ akp) {
  const int t = blockIdx.x * 256 + threadIdx.x;
  for (int i = t; i < NB * NL * ND / 4; i += gridDim.x * 256) {
    float4 f = ((const float4*)q)[i];
    ushort4 o; o.x = f2bf(f.x); o.y = f2bf(f.y); o.z = f2bf(f.z); o.w = f2bf(f.w);
    ((ushort4*)qb)[i] = o;
  }
  if (t < ND * ND / 4) {
    float4 f = ((const float4*)pt_w)[t];
    ushort4 o; o.x = f2bf(f.x); o.y = f2bf(f.y); o.z = f2bf(f.z); o.w = f2bf(f.w);
    ((ushort4*)ptb)[t] = o;
  }
  if (t < NH * NIPG * NIPG / 4) {
    float4 f = ((const float4*)pw_w)[t];
    ushort4 o; o.x = f2bf(f.x); o.y = f2bf(f.y); o.z = f2bf(f.z); o.w = f2bf(f.w);
    ((ushort4*)pwb)[t] = o;
  }
  if (t < NH * 16 * NIPG) {
    const int h = t >> 10;
    const int r = t & 1023;
    const int k = r >> 6;
    const int i = r & 63;
    akp[t] = (k < NK) ? f2bf(ak_w[((size_t)h * NK + k) * NIPG + i]) : (unsigned short)0;
  }
}

// ---------------------------------------------------------------------------
// Kernel 1: FUSED.  blockIdx < NGEMM: v-GEMM block (r5-proven 128x64 LDS-
// staged dbuf structure; writes v bf16 + bias).  blockIdx >= NGEMM: attn_w
// block (r8-proven body, reads qb bf16, writes w).  Heterogeneous blocks
// co-resident per CU -> attn VALU work hides gemm staging latency.
// ---------------------------------------------------------------------------
__global__ __launch_bounds__(256) void fused(const unsigned short* __restrict__ qb,
                                             const unsigned short* __restrict__ ptb,
                                             const float* __restrict__ bias,
                                             unsigned short* __restrict__ v,
                                             const float* __restrict__ dw_w,
                                             const unsigned short* __restrict__ pwb,
                                             const float* __restrict__ pw_b,
                                             const unsigned short* __restrict__ akp,
                                             const float* __restrict__ ak_b,
                                             float* __restrict__ wout) {
  __shared__ unsigned char smem[24576];
  const int t = threadIdx.x;
  const int lane = t & 63;
  const int wv = t >> 6;
  const int fr = lane & 15;
  const int fq = lane >> 4;

  if (blockIdx.x < NGEMM) {
    // ================= GEMM branch: v = qb . ptb^T + bias =================
    // XCD clustering: xcd x gets m-panels [x*8, x*8+8); 12 n-blocks each.
    const int g = blockIdx.x;
    const int xcd = g & 7;
    const int j = g >> 3;                 // 0..95
    const long mo = (long)(xcd * 8 + j / 12) * 128;
    const int n0 = (j % 12) * 64;

    const int soff = t * 16;
    const int sr = soff >> 6;
    const int scb = soff & 63;
    const unsigned char* gA0 = (const unsigned char*)qb + (mo + sr) * 1536L + scb;
    const unsigned char* gA1 = gA0 + 64L * 1536;
    const unsigned char* gB  = (const unsigned char*)ptb + (size_t)(n0 + sr) * 1536 + scb;

    int aoff[2], boff[4];
#pragma unroll
    for (int m = 0; m < 2; ++m)
      aoff[m] = ((wv * 32 + m * 16 + fr) * 32 + fq * 8) * 2;
#pragma unroll
    for (int n = 0; n < 4; ++n)
      boff[n] = 8192 + ((n * 16 + fr) * 32 + fq * 8) * 2;

#define STAGE(kt_, buf_)                                           \
    do {                                                           \
      const long kb_ = (long)(kt_) * 64;                           \
      unsigned char* base_ = &smem[(buf_) * 12288];                \
      gload16(gA0 + kb_, base_ + soff);                            \
      gload16(gA1 + kb_, base_ + 4096 + soff);                     \
      gload16(gB + kb_, base_ + 8192 + soff);                      \
    } while (0)

    f32x4 acc[2][4] = {};
    STAGE(0, 0);
    __syncthreads();
    for (int kt = 0; kt < ND / 32; ++kt) {
      const int cur = kt & 1;
      if (kt + 1 < ND / 32) STAGE(kt + 1, cur ^ 1);
      const unsigned char* bb = &smem[cur * 12288];
      s16x8 av[2], bv[4];
#pragma unroll
      for (int m = 0; m < 2; ++m) av[m] = *(const s16x8*)&bb[aoff[m]];
#pragma unroll
      for (int n = 0; n < 4; ++n) bv[n] = *(const s16x8*)&bb[boff[n]];
#pragma unroll
      for (int m = 0; m < 2; ++m)
#pragma unroll
        for (int n = 0; n < 4; ++n)
          acc[m][n] = __builtin_amdgcn_mfma_f32_16x16x32_bf16(av[m], bv[n], acc[m][n], 0, 0, 0);
      __syncthreads();
    }
#undef STAGE

    // epilogue: v bf16 (+bias).  C/D: col=lane&15, row=(lane>>4)*4+j
#pragma unroll
    for (int m = 0; m < 2; ++m) {
#pragma unroll
      for (int n = 0; n < 4; ++n) {
        const long row = mo + wv * 32 + m * 16 + fq * 4;
        const int col = n0 + n * 16 + fr;
        const float bbv = bias[col];
#pragma unroll
        for (int jj = 0; jj < 4; ++jj)
          v[(row + jj) * ND + col] = f2bf(acc[m][n][jj] + bbv);
      }
    }
  } else {
    // ================= ATTN branch (r8-proven, reads qb) =================
    const int a = blockIdx.x - NGEMM;
    const int l0 = (a & 31) * 64;
    const int h  = (a >> 5) % NH;
    const int b  = a / (32 * NH);
    const int d0 = h * NIPG;

    unsigned short (*qs)[68] = (unsigned short(*)[68])smem;   // 72x68 bf16
    unsigned char* ab = smem + 9792;                          // 8KB swizzled

    const unsigned short* pwh = pwb + (size_t)h * NIPG * NIPG;
    const unsigned short* akh = akp + (size_t)h * 16 * NIPG;
    s16x8 pv0[4], pv1[4];
#pragma unroll
    for (int n = 0; n < 4; ++n) {
      const int o = n * 16 + fr;
      pv0[n] = *(const s16x8*)&pwh[o * 64 + fq * 8];
      pv1[n] = *(const s16x8*)&pwh[o * 64 + 32 + fq * 8];
    }
    s16x8 ak0 = *(const s16x8*)&akh[fr * 64 + fq * 8];
    s16x8 ak1 = *(const s16x8*)&akh[fr * 64 + 32 + fq * 8];
    float dwk[NK];
#pragma unroll
    for (int k = 0; k < NK; ++k) dwk[k] = dw_w[(size_t)(d0 + lane) * NK + k];

    {
      const int sl = t >> 4;
      const int sc = (t & 15) * 4;
      for (int r = sl; r < 72; r += 16) {
        const int l = l0 - NPAD + r;
        ushort4 ub = make_ushort4(0, 0, 0, 0);
        if (l >= 0 && l < NL)
          ub = *(const ushort4*)&qb[((size_t)(b * NL + l)) * ND + d0 + sc];
        *(ushort4*)&qs[r][sc] = ub;
      }
    }
    __syncthreads();

    const int lset = wv * 16;
    {
      float win9[NK];
#pragma unroll
      for (int k = 0; k < NK; ++k) win9[k] = bf2f(qs[lset + k][lane]);
#pragma unroll
      for (int l2 = 0; l2 < 16; ++l2) {
        const int l = lset + l2;
        float s = 0.f;
#pragma unroll
        for (int k = 0; k < NK; ++k) s = fmaf(win9[k], dwk[k], s);
        const int byte = ((l * 64 + lane) * 2) ^ ((l & 7) << 4);
        *(unsigned short*)&ab[byte] = f2bf(s);
        if (l2 < 15) {
#pragma unroll
          for (int k = 0; k < NK - 1; ++k) win9[k] = win9[k + 1];
          win9[NK - 1] = bf2f(qs[lset + l2 + NK][lane]);
        }
      }
    }

    s16x8 av0, av1;
    {
      const int row = lset + fr;
      const int b0 = ((row * 64 + fq * 8) * 2)      ^ ((row & 7) << 4);
      const int b1 = ((row * 64 + 32 + fq * 8) * 2) ^ ((row & 7) << 4);
      av0 = *(const s16x8*)&ab[b0];
      av1 = *(const s16x8*)&ab[b1];
    }
    f32x4 accp[4];
#pragma unroll
    for (int n = 0; n < 4; ++n) {
      accp[n] = (f32x4){0.f, 0.f, 0.f, 0.f};
      accp[n] = __builtin_amdgcn_mfma_f32_16x16x32_bf16(av0, pv0[n], accp[n], 0, 0, 0);
      accp[n] = __builtin_amdgcn_mfma_f32_16x16x32_bf16(av1, pv1[n], accp[n], 0, 0, 0);
    }

#pragma unroll
    for (int n = 0; n < 4; ++n) {
      const int o = n * 16 + fr;
      const float pb = pw_b[d0 + o];
#pragma unroll
      for (int jj = 0; jj < 4; ++jj) {
        const int row = lset + fq * 4 + jj;
        const float ca = (accp[n][jj] + pb) * bf2f(qs[row + NPAD][o]);
        const int byte = ((row * 64 + o) * 2) ^ ((row & 7) << 4);
        *(unsigned short*)&ab[byte] = f2bf(ca);
      }
    }

    f32x4 acck = (f32x4){0.f, 0.f, 0.f, 0.f};
    {
      const int row = lset + fr;
      const int b0 = ((row * 64 + fq * 8) * 2)      ^ ((row & 7) << 4);
      const int b1 = ((row * 64 + 32 + fq * 8) * 2) ^ ((row & 7) << 4);
      s16x8 a0 = *(const s16x8*)&ab[b0];
      s16x8 a1 = *(const s16x8*)&ab[b1];
      acck = __builtin_amdgcn_mfma_f32_16x16x32_bf16(a0, ak0, acck, 0, 0, 0);
      acck = __builtin_amdgcn_mfma_f32_16x16x32_bf16(a1, ak1, acck, 0, 0, 0);
    }

    const bool kvalid = fr < NK;
    const float akbv = kvalid ? ak_b[h * NK + fr] : 0.f;
#pragma unroll
    for (int jj = 0; jj < 4; ++jj) {
      float val = acck[jj] + akbv;
      float mv = kvalid ? val : -3.4e38f;
#pragma unroll
      for (int mm = 1; mm < 16; mm <<= 1) mv = fmaxf(mv, __shfl_xor(mv, mm));
      const float e = kvalid ? __expf(val - mv) : 0.f;
      float ssum = e;
#pragma unroll
      for (int mm = 1; mm < 16; mm <<= 1) ssum += __shfl_xor(ssum, mm);
      if (kvalid) {
        const int row = l0 + lset + fq * 4 + jj;
        wout[(((size_t)(b * NL + row)) * NH + h) * NK + fr] = e / ssum;
      }
    }
  }
}

// ---------------------------------------------------------------------------
// Kernel 2: out[b,l,d] = sum_k w[b,l,h,k] * v[b,l+k-4,d]  (r3-proven rolling
// window; v bf16).
// ---------------------------------------------------------------------------
__global__ __launch_bounds__(192) void sdconv_out(const unsigned short* __restrict__ v,
                                                  const float* __restrict__ w,
                                                  float* __restrict__ out) {
  const int b  = blockIdx.y;
  const int l0 = blockIdx.x * LT;
  const int t  = threadIdx.x;          // 0..191
  const int d  = t * 4;
  const int h  = t >> 4;
  const size_t vbase = (size_t)b * NL * ND + d;

  float4 win[NK];
#pragma unroll
  for (int k = 0; k < NK; ++k) {
    const int r = l0 - NPAD + k;
    if (r >= 0 && r < NL) {
      ushort4 u = *(const ushort4*)&v[vbase + (size_t)r * ND];
      win[k] = make_float4(bf2f(u.x), bf2f(u.y), bf2f(u.z), bf2f(u.w));
    } else {
      win[k] = make_float4(0.f, 0.f, 0.f, 0.f);
    }
  }
#pragma unroll
  for (int l2 = 0; l2 < LT; ++l2) {
    const int l = l0 + l2;
    const float* wp = &w[(((size_t)(b * NL + l)) * NH + h) * NK];
    float4 acc = make_float4(0.f, 0.f, 0.f, 0.f);
#pragma unroll
    for (int k = 0; k < NK; ++k) {
      const float wk = wp[k];
      acc.x = fmaf(wk, win[k].x, acc.x);
      acc.y = fmaf(wk, win[k].y, acc.y);
      acc.z = fmaf(wk, win[k].z, acc.z);
      acc.w = fmaf(wk, win[k].w, acc.w);
    }
    *(float4*)&out[(size_t)(b * NL + l) * ND + d] = acc;
#pragma unroll
    for (int k = 0; k < NK - 1; ++k) win[k] = win[k + 1];
    const int rn = l + NPAD + 1;
    if (rn < NL) {
      ushort4 u = *(const ushort4*)&v[vbase + (size_t)rn * ND];
      win[NK - 1] = make_float4(bf2f(u.x), bf2f(u.y), bf2f(u.z), bf2f(u.w));
    } else {
      win[NK - 1] = make_float4(0.f, 0.f, 0.f, 0.f);
    }
  }
}

// ---------------------------------------------------------------------------
extern "C" void kernel_launch(void* const* d_in, const int* in_sizes, int n_in,
                              void* d_out, int out_size, void* d_ws, size_t ws_size,
                              hipStream_t stream) {
  const float* query = (const float*)d_in[0];
  const float* dw_w  = (const float*)d_in[1];
  const float* pw_w  = (const float*)d_in[2];
  const float* pw_b  = (const float*)d_in[3];
  const float* ak_w  = (const float*)d_in[4];
  const float* ak_b  = (const float*)d_in[5];
  const float* pt_w  = (const float*)d_in[6];
  const float* pt_b  = (const float*)d_in[7];
  float* out = (float*)d_out;

  // workspace layout (~30.5 MB of 268 MB)
  float* w = (float*)d_ws;                                        // 3.54MB
  unsigned short* qb  = (unsigned short*)(w + (size_t)NB * NL * NH * NK); // 12.6MB
  unsigned short* ptb = qb + (size_t)NB * NL * ND;                // 1.18MB
  unsigned short* pwb = ptb + (size_t)ND * ND;                    // 98KB
  unsigned short* akp = pwb + (size_t)NH * NIPG * NIPG;           // 24.6KB
  unsigned short* v   = akp + (size_t)NH * 16 * NIPG;             // 12.6MB bf16

  prep<<<2048, 256, 0, stream>>>(query, pt_w, pw_w, ak_w, qb, ptb, pwb, akp);

  fused<<<NGEMM + 32 * NH * NB, 256, 0, stream>>>(qb, ptb, pt_b, v,
                                                  dw_w, pwb, pw_b, akp, ak_b, w);

  dim3 g3(NL / LT, NB, 1);
  sdconv_out<<<g3, 192, 0, stream>>>(v, w, out);
}

// Round 12
// 138.623 us; speedup vs baseline: 1.2322x; 1.0090x over previous
//
#include <hip/hip_runtime.h>
#include <math.h>

#define NB 4
#define NL 2048
#define ND 768
#define NH 12
#define NK 9
#define NIPG 64
#define NPAD 4
#define LT 16
#define NGEMM 768     // gemm blocks in fused launch (64 m-panels x 12 n)

typedef __attribute__((ext_vector_type(8))) short s16x8;
typedef __attribute__((ext_vector_type(4))) float f32x4;

__device__ __forceinline__ unsigned short f2bf(float f) {
  unsigned int u = __float_as_uint(f);
  unsigned int r = (u + 0x7FFFu + ((u >> 16) & 1u)) >> 16;
  return (unsigned short)r;
}
__device__ __forceinline__ float bf2f(unsigned short s) {
  return __uint_as_float(((unsigned int)s) << 16);
}
__device__ __forceinline__ void gload16(const void* g, void* l) {
  __builtin_amdgcn_global_load_lds((const __attribute__((address_space(1))) void*)g,
                                   (__attribute__((address_space(3))) void*)l,
                                   16, 0, 0);
}

// ---------------------------------------------------------------------------
// Kernel 0: prep — q -> qb (bf16, grid-stride), pt_w -> ptb, pw_w -> pwb,
// ak_w -> akp (k-padded to 16).
// ---------------------------------------------------------------------------
__global__ __launch_bounds__(256) void prep(const float* __restrict__ q,
                                            const float* __restrict__ pt_w,
                                            const float* __restrict__ pw_w,
                                            const float* __restrict__ ak_w,
                                            unsigned short* __restrict__ qb,
                                            unsigned short* __restrict__ ptb,
                                            unsigned short* __restrict__ pwb,
                                            unsigned short* __restrict__ akp) {
  const int t = blockIdx.x * 256 + threadIdx.x;
  for (int i = t; i < NB * NL * ND / 4; i += gridDim.x * 256) {
    float4 f = ((const float4*)q)[i];
    ushort4 o; o.x = f2bf(f.x); o.y = f2bf(f.y); o.z = f2bf(f.z); o.w = f2bf(f.w);
    ((ushort4*)qb)[i] = o;
  }
  if (t < ND * ND / 4) {
    float4 f = ((const float4*)pt_w)[t];
    ushort4 o; o.x = f2bf(f.x); o.y = f2bf(f.y); o.z = f2bf(f.z); o.w = f2bf(f.w);
    ((ushort4*)ptb)[t] = o;
  }
  if (t < NH * NIPG * NIPG / 4) {
    float4 f = ((const float4*)pw_w)[t];
    ushort4 o; o.x = f2bf(f.x); o.y = f2bf(f.y); o.z = f2bf(f.z); o.w = f2bf(f.w);
    ((ushort4*)pwb)[t] = o;
  }
  if (t < NH * 16 * NIPG) {
    const int h = t >> 10;
    const int r = t & 1023;
    const int k = r >> 6;
    const int i = r & 63;
    akp[t] = (k < NK) ? f2bf(ak_w[((size_t)h * NK + k) * NIPG + i]) : (unsigned short)0;
  }
}

// ---------------------------------------------------------------------------
// Kernel 1: FUSED.  blockIdx < NGEMM: v-GEMM block; blockIdx >= NGEMM: attn_w
// block.  GEMM K-loop uses counted-vmcnt (T3/T4): vmcnt(3) + raw s_barrier so
// the prefetched tile's 3 global_load_lds stay in flight across the barrier
// (plain __syncthreads drains vmcnt to 0 every step, nullifying the dbuf).
// K-loop has NO other vmem ops -> count clean.
// ---------------------------------------------------------------------------
__global__ __launch_bounds__(256) void fused(const unsigned short* __restrict__ qb,
                                             const unsigned short* __restrict__ ptb,
                                             const float* __restrict__ bias,
                                             unsigned short* __restrict__ v,
                                             const float* __restrict__ dw_w,
                                             const unsigned short* __restrict__ pwb,
                                             const float* __restrict__ pw_b,
                                             const unsigned short* __restrict__ akp,
                                             const float* __restrict__ ak_b,
                                             float* __restrict__ wout) {
  __shared__ unsigned char smem[24576];
  const int t = threadIdx.x;
  const int lane = t & 63;
  const int wv = t >> 6;
  const int fr = lane & 15;
  const int fq = lane >> 4;

  if (blockIdx.x < NGEMM) {
    // ================= GEMM branch: v = qb . ptb^T + bias =================
    const int g = blockIdx.x;
    const int xcd = g & 7;
    const int j = g >> 3;                 // 0..95
    const long mo = (long)(xcd * 8 + j / 12) * 128;
    const int n0 = (j % 12) * 64;

    const int soff = t * 16;
    const int sr = soff >> 6;
    const int scb = soff & 63;
    const unsigned char* gA0 = (const unsigned char*)qb + (mo + sr) * 1536L + scb;
    const unsigned char* gA1 = gA0 + 64L * 1536;
    const unsigned char* gB  = (const unsigned char*)ptb + (size_t)(n0 + sr) * 1536 + scb;

    int aoff[2], boff[4];
#pragma unroll
    for (int m = 0; m < 2; ++m)
      aoff[m] = ((wv * 32 + m * 16 + fr) * 32 + fq * 8) * 2;
#pragma unroll
    for (int n = 0; n < 4; ++n)
      boff[n] = 8192 + ((n * 16 + fr) * 32 + fq * 8) * 2;

#define STAGE(kt_)                                                 \
    do {                                                           \
      const long kb_ = (long)(kt_) * 64;                           \
      unsigned char* base_ = &smem[((kt_) & 1) * 12288];           \
      gload16(gA0 + kb_, base_ + soff);                            \
      gload16(gA1 + kb_, base_ + 4096 + soff);                     \
      gload16(gB + kb_, base_ + 8192 + soff);                      \
    } while (0)

#define FRAGS(kt_)                                                 \
    do {                                                           \
      const unsigned char* bb_ = &smem[((kt_) & 1) * 12288];       \
      _Pragma("unroll")                                            \
      for (int m_ = 0; m_ < 2; ++m_) av[m_] = *(const s16x8*)&bb_[aoff[m_]]; \
      _Pragma("unroll")                                            \
      for (int n_ = 0; n_ < 4; ++n_) bv[n_] = *(const s16x8*)&bb_[boff[n_]]; \
    } while (0)

#define MM8                                                        \
    do {                                                           \
      _Pragma("unroll")                                            \
      for (int m_ = 0; m_ < 2; ++m_)                               \
        _Pragma("unroll")                                          \
        for (int n_ = 0; n_ < 4; ++n_)                             \
          acc[m_][n_] = __builtin_amdgcn_mfma_f32_16x16x32_bf16(   \
              av[m_], bv[n_], acc[m_][n_], 0, 0, 0);               \
    } while (0)

    f32x4 acc[2][4] = {};
    s16x8 av[2], bv[4];

    STAGE(0);
    STAGE(1);                              // 6 loads in flight
    for (int kt = 0; kt < 23; ++kt) {
      asm volatile("s_waitcnt vmcnt(3)" ::: "memory");  // oldest tile done; next stays in flight
      __builtin_amdgcn_s_barrier();                     // tile kt visible to all waves
      FRAGS(kt);
      asm volatile("s_waitcnt lgkmcnt(0)" ::: "memory");
      __builtin_amdgcn_sched_barrier(0);
      __builtin_amdgcn_s_barrier();                     // all waves' reads of buf kt done
      if (kt + 2 < 24) STAGE(kt + 2);                   // overwrite buf kt; 6 in flight again
      MM8;
    }
    {  // kt = 23 (peeled: only its own 3 loads remain)
      asm volatile("s_waitcnt vmcnt(0)" ::: "memory");
      __builtin_amdgcn_s_barrier();
      FRAGS(23);
      MM8;
    }
#undef STAGE
#undef FRAGS
#undef MM8

    // epilogue: v bf16 (+bias).  C/D: col=lane&15, row=(lane>>4)*4+j
#pragma unroll
    for (int m = 0; m < 2; ++m) {
#pragma unroll
      for (int n = 0; n < 4; ++n) {
        const long row = mo + wv * 32 + m * 16 + fq * 4;
        const int col = n0 + n * 16 + fr;
        const float bbv = bias[col];
#pragma unroll
        for (int jj = 0; jj < 4; ++jj)
          v[(row + jj) * ND + col] = f2bf(acc[m][n][jj] + bbv);
      }
    }
  } else {
    // ================= ATTN branch (r8/r9-proven, reads qb) =================
    const int a = blockIdx.x - NGEMM;
    const int l0 = (a & 31) * 64;
    const int h  = (a >> 5) % NH;
    const int b  = a / (32 * NH);
    const int d0 = h * NIPG;

    unsigned short (*qs)[68] = (unsigned short(*)[68])smem;   // 72x68 bf16
    unsigned char* ab = smem + 9792;                          // 8KB swizzled

    const unsigned short* pwh = pwb + (size_t)h * NIPG * NIPG;
    const unsigned short* akh = akp + (size_t)h * 16 * NIPG;
    s16x8 pv0[4], pv1[4];
#pragma unroll
    for (int n = 0; n < 4; ++n) {
      const int o = n * 16 + fr;
      pv0[n] = *(const s16x8*)&pwh[o * 64 + fq * 8];
      pv1[n] = *(const s16x8*)&pwh[o * 64 + 32 + fq * 8];
    }
    s16x8 ak0 = *(const s16x8*)&akh[fr * 64 + fq * 8];
    s16x8 ak1 = *(const s16x8*)&akh[fr * 64 + 32 + fq * 8];
    float dwk[NK];
#pragma unroll
    for (int k = 0; k < NK; ++k) dwk[k] = dw_w[(size_t)(d0 + lane) * NK + k];

    {
      const int sl = t >> 4;
      const int sc = (t & 15) * 4;
      for (int r = sl; r < 72; r += 16) {
        const int l = l0 - NPAD + r;
        ushort4 ub = make_ushort4(0, 0, 0, 0);
        if (l >= 0 && l < NL)
          ub = *(const ushort4*)&qb[((size_t)(b * NL + l)) * ND + d0 + sc];
        *(ushort4*)&qs[r][sc] = ub;
      }
    }
    __syncthreads();

    const int lset = wv * 16;
    {
      float win9[NK];
#pragma unroll
      for (int k = 0; k < NK; ++k) win9[k] = bf2f(qs[lset + k][lane]);
#pragma unroll
      for (int l2 = 0; l2 < 16; ++l2) {
        const int l = lset + l2;
        float s = 0.f;
#pragma unroll
        for (int k = 0; k < NK; ++k) s = fmaf(win9[k], dwk[k], s);
        const int byte = ((l * 64 + lane) * 2) ^ ((l & 7) << 4);
        *(unsigned short*)&ab[byte] = f2bf(s);
        if (l2 < 15) {
#pragma unroll
          for (int k = 0; k < NK - 1; ++k) win9[k] = win9[k + 1];
          win9[NK - 1] = bf2f(qs[lset + l2 + NK][lane]);
        }
      }
    }

    s16x8 av0, av1;
    {
      const int row = lset + fr;
      const int b0 = ((row * 64 + fq * 8) * 2)      ^ ((row & 7) << 4);
      const int b1 = ((row * 64 + 32 + fq * 8) * 2) ^ ((row & 7) << 4);
      av0 = *(const s16x8*)&ab[b0];
      av1 = *(const s16x8*)&ab[b1];
    }
    f32x4 accp[4];
#pragma unroll
    for (int n = 0; n < 4; ++n) {
      accp[n] = (f32x4){0.f, 0.f, 0.f, 0.f};
      accp[n] = __builtin_amdgcn_mfma_f32_16x16x32_bf16(av0, pv0[n], accp[n], 0, 0, 0);
      accp[n] = __builtin_amdgcn_mfma_f32_16x16x32_bf16(av1, pv1[n], accp[n], 0, 0, 0);
    }

#pragma unroll
    for (int n = 0; n < 4; ++n) {
      const int o = n * 16 + fr;
      const float pb = pw_b[d0 + o];
#pragma unroll
      for (int jj = 0; jj < 4; ++jj) {
        const int row = lset + fq * 4 + jj;
        const float ca = (accp[n][jj] + pb) * bf2f(qs[row + NPAD][o]);
        const int byte = ((row * 64 + o) * 2) ^ ((row & 7) << 4);
        *(unsigned short*)&ab[byte] = f2bf(ca);
      }
    }

    f32x4 acck = (f32x4){0.f, 0.f, 0.f, 0.f};
    {
      const int row = lset + fr;
      const int b0 = ((row * 64 + fq * 8) * 2)      ^ ((row & 7) << 4);
      const int b1 = ((row * 64 + 32 + fq * 8) * 2) ^ ((row & 7) << 4);
      s16x8 a0 = *(const s16x8*)&ab[b0];
      s16x8 a1 = *(const s16x8*)&ab[b1];
      acck = __builtin_amdgcn_mfma_f32_16x16x32_bf16(a0, ak0, acck, 0, 0, 0);
      acck = __builtin_amdgcn_mfma_f32_16x16x32_bf16(a1, ak1, acck, 0, 0, 0);
    }

    const bool kvalid = fr < NK;
    const float akbv = kvalid ? ak_b[h * NK + fr] : 0.f;
#pragma unroll
    for (int jj = 0; jj < 4; ++jj) {
      float val = acck[jj] + akbv;
      float mv = kvalid ? val : -3.4e38f;
#pragma unroll
      for (int mm = 1; mm < 16; mm <<= 1) mv = fmaxf(mv, __shfl_xor(mv, mm));
      const float e = kvalid ? __expf(val - mv) : 0.f;
      float ssum = e;
#pragma unroll
      for (int mm = 1; mm < 16; mm <<= 1) ssum += __shfl_xor(ssum, mm);
      if (kvalid) {
        const int row = l0 + lset + fq * 4 + jj;
        wout[(((size_t)(b * NL + row)) * NH + h) * NK + fr] = e / ssum;
      }
    }
  }
}

// ---------------------------------------------------------------------------
// Kernel 2: out[b,l,d] = sum_k w[b,l,h,k] * v[b,l+k-4,d]  (r3-proven rolling
// window; v bf16).
// ---------------------------------------------------------------------------
__global__ __launch_bounds__(192) void sdconv_out(const unsigned short* __restrict__ v,
                                                  const float* __restrict__ w,
                                                  float* __restrict__ out) {
  const int b  = blockIdx.y;
  const int l0 = blockIdx.x * LT;
  const int t  = threadIdx.x;          // 0..191
  const int d  = t * 4;
  const int h  = t >> 4;
  const size_t vbase = (size_t)b * NL * ND + d;

  float4 win[NK];
#pragma unroll
  for (int k = 0; k < NK; ++k) {
    const int r = l0 - NPAD + k;
    if (r >= 0 && r < NL) {
      ushort4 u = *(const ushort4*)&v[vbase + (size_t)r * ND];
      win[k] = make_float4(bf2f(u.x), bf2f(u.y), bf2f(u.z), bf2f(u.w));
    } else {
      win[k] = make_float4(0.f, 0.f, 0.f, 0.f);
    }
  }
#pragma unroll
  for (int l2 = 0; l2 < LT; ++l2) {
    const int l = l0 + l2;
    const float* wp = &w[(((size_t)(b * NL + l)) * NH + h) * NK];
    float4 acc = make_float4(0.f, 0.f, 0.f, 0.f);
#pragma unroll
    for (int k = 0; k < NK; ++k) {
      const float wk = wp[k];
      acc.x = fmaf(wk, win[k].x, acc.x);
      acc.y = fmaf(wk, win[k].y, acc.y);
      acc.z = fmaf(wk, win[k].z, acc.z);
      acc.w = fmaf(wk, win[k].w, acc.w);
    }
    *(float4*)&out[(size_t)(b * NL + l) * ND + d] = acc;
#pragma unroll
    for (int k = 0; k < NK - 1; ++k) win[k] = win[k + 1];
    const int rn = l + NPAD + 1;
    if (rn < NL) {
      ushort4 u = *(const ushort4*)&v[vbase + (size_t)rn * ND];
      win[NK - 1] = make_float4(bf2f(u.x), bf2f(u.y), bf2f(u.z), bf2f(u.w));
    } else {
      win[NK - 1] = make_float4(0.f, 0.f, 0.f, 0.f);
    }
  }
}

// ---------------------------------------------------------------------------
extern "C" void kernel_launch(void* const* d_in, const int* in_sizes, int n_in,
                              void* d_out, int out_size, void* d_ws, size_t ws_size,
                              hipStream_t stream) {
  const float* query = (const float*)d_in[0];
  const float* dw_w  = (const float*)d_in[1];
  const float* pw_w  = (const float*)d_in[2];
  const float* pw_b  = (const float*)d_in[3];
  const float* ak_w  = (const float*)d_in[4];
  const float* ak_b  = (const float*)d_in[5];
  const float* pt_w  = (const float*)d_in[6];
  const float* pt_b  = (const float*)d_in[7];
  float* out = (float*)d_out;

  // workspace layout (~30.5 MB of 268 MB)
  float* w = (float*)d_ws;                                        // 3.54MB
  unsigned short* qb  = (unsigned short*)(w + (size_t)NB * NL * NH * NK); // 12.6MB
  unsigned short* ptb = qb + (size_t)NB * NL * ND;                // 1.18MB
  unsigned short* pwb = ptb + (size_t)ND * ND;                    // 98KB
  unsigned short* akp = pwb + (size_t)NH * NIPG * NIPG;           // 24.6KB
  unsigned short* v   = akp + (size_t)NH * 16 * NIPG;             // 12.6MB bf16

  prep<<<2048, 256, 0, stream>>>(query, pt_w, pw_w, ak_w, qb, ptb, pwb, akp);

  fused<<<NGEMM + 32 * NH * NB, 256, 0, stream>>>(qb, ptb, pt_b, v,
                                                  dw_w, pwb, pw_b, akp, ak_b, w);

  dim3 g3(NL / LT, NB, 1);
  sdconv_out<<<g3, 192, 0, stream>>>(v, w, out);
}